// Round 2
// baseline (3839.900 us; speedup 1.0000x reference)
//
#include <hip/hip_runtime.h>
#include <hip/hip_bf16.h>

#define D 128

typedef unsigned short u16;
typedef unsigned int   u32;
typedef unsigned long long u64;

__device__ __forceinline__ float bf2f(u16 u) {
    union { u32 i; float f; } v; v.i = ((u32)u) << 16; return v.f;
}
__device__ __forceinline__ float bflo(u32 p) {
    union { u32 i; float f; } v; v.i = p << 16; return v.f;
}
__device__ __forceinline__ float bfhi(u32 p) {
    union { u32 i; float f; } v; v.i = p & 0xffff0000u; return v.f;
}
__device__ __forceinline__ u16 f2bf(float f) {
    union { float f; u32 i; } v; v.f = f;
    return (u16)((v.i + 0x7fffu + ((v.i >> 16) & 1u)) >> 16);
}
// dtype-flexible scalar load: isb ? bf16 : f32
__device__ __forceinline__ float ldf(const void* p, long i, int isb) {
    return isb ? bf2f(((const u16*)p)[i]) : ((const float*)p)[i];
}

__device__ __forceinline__ float sigm(float x) { return 1.0f / (1.0f + __expf(-x)); }
__device__ __forceinline__ float tanh_fast(float x) {
    float a = fabsf(x);
    float t = __expf(-2.0f * a);
    float r = (1.0f - t) / (1.0f + t);
    return copysignf(r, x);
}

// harness-visible symbol (defined but not required to launch)
__global__ void DRlocal_net_79173427135059_kernel() {}

// K-1: runtime dtype detection. flag[0]=float-inputs-are-bf16, flag[1]=node_id-is-int64.
// bf16 data read as u16: ~100% of values have sane magnitude. f32 data read as u16
// halves: only the 32 high-halves are sane (~50%). Threshold at 48/64.
__global__ __launch_bounds__(64) void k_detect(const void* ent, const void* nid, int* flag) {
    int lane = threadIdx.x;
    float a = fabsf(bf2f(((const u16*)ent)[lane]));
    bool sane = (a >= 9.765625e-4f && a <= 64.0f);
    u64 m = __ballot(sane);
    // int64 node_id => every odd u32 word is a zero high-word (values < 2^18)
    u32 w = ((const u32*)nid)[lane];
    bool oddzero = ((lane & 1) == 0) || (w == 0u);
    u64 m2 = __ballot(oddzero);
    if (lane == 0) {
        flag[0] = (__popcll(m) >= 48) ? 1 : 0;
        flag[1] = (m2 == ~0ull) ? 1 : 0;
    }
}

// K0: convert W + GRU weights/biases to f32 (weights transposed to [K][384]).
__global__ __launch_bounds__(256) void k_prep(
    const void* __restrict__ w_ih, const void* __restrict__ w_hh,
    const void* __restrict__ b_ih, const void* __restrict__ b_hh,
    const void* __restrict__ W, const int* __restrict__ flag,
    float* __restrict__ Wf, float* __restrict__ wTih, float* __restrict__ wThh,
    float* __restrict__ bif, float* __restrict__ bhf)
{
    int isb = flag[0];
    int t = blockIdx.x * 256 + threadIdx.x;
    if (t < 16384) { Wf[t] = ldf(W, t, isb); return; }
    int u = t - 16384;
    if (u < 98304) { int k = u / 384, j = u % 384; wTih[u] = ldf(w_ih, (long)j * 256 + k, isb); return; }
    int v = u - 98304;
    if (v < 49152) { int k = v / 384, j = v % 384; wThh[v] = ldf(w_hh, (long)j * 128 + k, isb); return; }
    int b = v - 49152;
    if (b < 384) { bif[b] = ldf(b_ih, b, isb); return; }
    int c = b - 384;
    if (c < 384) { bhf[c] = ldf(b_hh, c, isb); return; }
}

// K0b: zero agg (no hipMemsetAsync — keep graph capture trivially safe)
__global__ __launch_bounds__(256) void k_zero(float4* __restrict__ agg, int n4) {
    int t = blockIdx.x * 256 + threadIdx.x;
    if (t < n4) agg[t] = make_float4(0.f, 0.f, 0.f, 0.f);
}

// K1: hW[n] = ent_embs[node_id[n]] @ W  (4 nodes/block, one wave per node; hW stored bf16)
__global__ __launch_bounds__(256) void k_gmm(
    const void* __restrict__ ent, const void* __restrict__ node_id,
    const float* __restrict__ Wf, u16* __restrict__ hW,
    const int* __restrict__ flag, int N)
{
    __shared__ float hs[4][D];
    int isb = flag[0], i64 = flag[1];
    int tid = threadIdx.x, r = tid >> 6, lane = tid & 63;
    int n = blockIdx.x * 4 + r;
    if (n < N) {
        long nid = i64 ? (long)((const long long*)node_id)[n]
                       : (long)((const int*)node_id)[n];
        long base2 = nid * (D / 2) + lane;   // index of 2-element group
        if (isb) {
            u32 hv = ((const u32*)ent)[base2];
            hs[r][2 * lane] = bflo(hv); hs[r][2 * lane + 1] = bfhi(hv);
        } else {
            float2 hv = ((const float2*)ent)[base2];
            hs[r][2 * lane] = hv.x; hs[r][2 * lane + 1] = hv.y;
        }
    }
    __syncthreads();
    if (n >= N) return;
    float a0 = 0.f, a1 = 0.f;
    const float2* W2 = (const float2*)Wf;   // cols (2*lane, 2*lane+1)
    #pragma unroll 8
    for (int k = 0; k < D; ++k) {
        float2 w = W2[k * 64 + lane];
        float h = hs[r][k];
        a0 += h * w.x; a1 += h * w.y;
    }
    ((u32*)hW)[(size_t)n * 64 + lane] = ((u32)f2bf(a1) << 16) | (u32)f2bf(a0);
}

// K3: agg[dst] += hW[src]  (32 threads/edge, 4 dims each, f32 atomics)
__global__ __launch_bounds__(256) void k_scatter(
    const u16* __restrict__ hW, const int* __restrict__ esrc,
    const int* __restrict__ edst, float* __restrict__ agg, int E)
{
    int t = blockIdx.x * 256 + threadIdx.x;
    int e = t >> 5;
    if (e >= E) return;
    int sub = t & 31;
    int s = esrc[e], d = edst[e];
    uint2 v = ((const uint2*)(hW + (size_t)s * D))[sub];
    float* q = agg + (size_t)d * D + sub * 4;
    atomicAdd(q + 0, bflo(v.x));
    atomicAdd(q + 1, bfhi(v.x));
    atomicAdd(q + 2, bflo(v.y));
    atomicAdd(q + 3, bfhi(v.y));
}

// K4: fused GRU + relu + L2-normalize. 8 nodes per 384-thread block.
__global__ __launch_bounds__(384) void k_epi(
    const float* __restrict__ agg, const void* __restrict__ bias,
    const void* __restrict__ onorm, const float* __restrict__ wTih,
    const float* __restrict__ wThh, const float* __restrict__ bif,
    const float* __restrict__ bhf, void* __restrict__ out,
    const int* __restrict__ flag, int N)
{
    __shared__ __align__(16) float xsT[256][8];  // x transposed: [agg*onorm ; e_r_bias]
    __shared__ float ga[8][384];                 // gx
    __shared__ float gb[8][384];                 // gh
    __shared__ float inv8[8];
    int isb = flag[0];
    int tid = threadIdx.x;
    int n0  = blockIdx.x * 8;

    // phase 1: stage x (transposed) in LDS
    for (int idx = tid; idx < 2048; idx += 384) {
        int n = idx >> 8, k = idx & 255;
        int gn = n0 + n;
        float v = 0.f;
        if (gn < N) {
            if (k < 128) v = agg[(size_t)gn * D + k] * ldf(onorm, gn, isb);
            else         v = ldf(bias, (long)gn * D + (k - 128), isb);
        }
        xsT[k][n] = v;
    }
    __syncthreads();

    // phase 2: matvecs; gate row j = tid, 8 nodes in registers
    {
        int j = tid;
        float ax[8], ah[8];
        #pragma unroll
        for (int n = 0; n < 8; ++n) { ax[n] = 0.f; ah[n] = 0.f; }
        #pragma unroll 4
        for (int k = 0; k < 256; ++k) {
            float w = wTih[k * 384 + j];
            const float4* xp = reinterpret_cast<const float4*>(&xsT[k][0]);
            float4 x0 = xp[0], x1 = xp[1];
            ax[0] += w * x0.x; ax[1] += w * x0.y; ax[2] += w * x0.z; ax[3] += w * x0.w;
            ax[4] += w * x1.x; ax[5] += w * x1.y; ax[6] += w * x1.z; ax[7] += w * x1.w;
        }
        #pragma unroll 4
        for (int k = 0; k < 128; ++k) {
            float w = wThh[k * 384 + j];
            const float4* xp = reinterpret_cast<const float4*>(&xsT[128 + k][0]);
            float4 x0 = xp[0], x1 = xp[1];
            ah[0] += w * x0.x; ah[1] += w * x0.y; ah[2] += w * x0.z; ah[3] += w * x0.w;
            ah[4] += w * x1.x; ah[5] += w * x1.y; ah[6] += w * x1.z; ah[7] += w * x1.w;
        }
        float bi = bif[j], bh = bhf[j];
        #pragma unroll
        for (int n = 0; n < 8; ++n) { ga[n][j] = ax[n] + bi; gb[n][j] = ah[n] + bh; }
    }
    __syncthreads();

    // phase 3: gates + GRU combine + relu; h0 overwrites ga[n][0:128]
    for (int idx = tid; idx < 1024; idx += 384) {
        int n = idx >> 7, dd = idx & 127;
        float r  = sigm(ga[n][dd] + gb[n][dd]);
        float z  = sigm(ga[n][128 + dd] + gb[n][128 + dd]);
        float ng = tanh_fast(ga[n][256 + dd] + r * gb[n][256 + dd]);
        float h  = xsT[128 + dd][n];
        float h0 = (1.f - z) * ng + z * h;
        ga[n][dd] = fmaxf(h0, 0.f);
    }
    __syncthreads();

    // phase 4: per-node L2 norm (32 threads/node)
    if (tid < 256) {
        int n = tid >> 5, l = tid & 31;
        float ss = 0.f;
        #pragma unroll
        for (int i = 0; i < 4; ++i) { float v = ga[n][l + 32 * i]; ss += v * v; }
        #pragma unroll
        for (int off = 16; off >= 1; off >>= 1) ss += __shfl_xor(ss, off, 32);
        if (l == 0) inv8[n] = 1.f / fmaxf(sqrtf(ss), 1e-12f);
    }
    __syncthreads();

    // phase 5: scale + store (dtype per flag)
    for (int idx = tid; idx < 1024; idx += 384) {
        int n = idx >> 7, dd = idx & 127;
        int gn = n0 + n;
        if (gn < N) {
            float v = ga[n][dd] * inv8[n];
            if (isb) ((u16*)out)[(size_t)gn * D + dd] = f2bf(v);
            else     ((float*)out)[(size_t)gn * D + dd] = v;
        }
    }
}

extern "C" void kernel_launch(void* const* d_in, const int* in_sizes, int n_in,
                              void* d_out, int out_size, void* d_ws, size_t ws_size,
                              hipStream_t stream) {
    const void* ent     = d_in[0];
    const void* bias    = d_in[2];
    const void* onorm   = d_in[3];
    const void* W       = d_in[4];
    const void* w_ih    = d_in[5];
    const void* w_hh    = d_in[6];
    const void* b_ih    = d_in[7];
    const void* b_hh    = d_in[8];
    const void* node_id = d_in[9];
    const int*  esrc    = (const int*)d_in[10];
    const int*  edst    = (const int*)d_in[11];

    int N = in_sizes[2] / D;     // 100000
    int E = in_sizes[10];        // 1600000

    char* ws = (char*)d_ws;
    int*   flag = (int*)ws;                          // 64 B
    float* Wf   = (float*)(ws + 64);                 // 16384 f = 65536 B
    float* wTih = (float*)(ws + 65600);              // 98304 f = 393216 B
    float* wThh = (float*)(ws + 458816);             // 49152 f = 196608 B
    float* bif  = (float*)(ws + 655424);             // 384 f (pad to 2048 B)
    float* bhf  = (float*)(ws + 657472);             // 384 f (pad to 2048 B)
    u16*   hW   = (u16*)(ws + 659520);               // N*128 bf16 = 25.6 MB
    float* agg  = (float*)(ws + 659520 + (size_t)N * D * 2);  // N*128 f32 = 51.2 MB

    k_detect<<<1, 64, 0, stream>>>(ent, node_id, flag);
    k_prep<<<643, 256, 0, stream>>>(w_ih, w_hh, b_ih, b_hh, W, flag,
                                    Wf, wTih, wThh, bif, bhf);
    int n4 = N * D / 4;
    k_zero<<<(n4 + 255) / 256, 256, 0, stream>>>((float4*)agg, n4);
    k_gmm<<<(N + 3) / 4, 256, 0, stream>>>(ent, node_id, Wf, hW, flag, N);
    long long st = (long long)E * 32;
    k_scatter<<<(int)((st + 255) / 256), 256, 0, stream>>>(hW, esrc, edst, agg, E);
    k_epi<<<(N + 7) / 8, 384, 0, stream>>>(agg, bias, onorm, wTih, wThh, bif, bhf,
                                           d_out, flag, N);
}

// Round 3
// 1405.369 us; speedup vs baseline: 2.7323x; 2.7323x over previous
//
#include <hip/hip_runtime.h>
#include <hip/hip_bf16.h>

#define D 128

typedef unsigned short u16;
typedef unsigned int   u32;
typedef unsigned long long u64;

__device__ __forceinline__ float bf2f(u16 u) {
    union { u32 i; float f; } v; v.i = ((u32)u) << 16; return v.f;
}
__device__ __forceinline__ float bflo(u32 p) {
    union { u32 i; float f; } v; v.i = p << 16; return v.f;
}
__device__ __forceinline__ float bfhi(u32 p) {
    union { u32 i; float f; } v; v.i = p & 0xffff0000u; return v.f;
}
__device__ __forceinline__ u16 f2bf(float f) {
    union { float f; u32 i; } v; v.f = f;
    return (u16)((v.i + 0x7fffu + ((v.i >> 16) & 1u)) >> 16);
}
__device__ __forceinline__ float ldf(const void* p, long i, int isb) {
    return isb ? bf2f(((const u16*)p)[i]) : ((const float*)p)[i];
}

__device__ __forceinline__ float sigm(float x) { return 1.0f / (1.0f + __expf(-x)); }
__device__ __forceinline__ float tanh_fast(float x) {
    float a = fabsf(x);
    float t = __expf(-2.0f * a);
    float r = (1.0f - t) / (1.0f + t);
    return copysignf(r, x);
}

__global__ void DRlocal_net_79173427135059_kernel() {}

// K-1: runtime dtype detection. flag[0]=inputs-are-bf16, flag[1]=node_id-is-int64.
__global__ __launch_bounds__(64) void k_detect(const void* ent, const void* nid, int* flag) {
    int lane = threadIdx.x;
    float a = fabsf(bf2f(((const u16*)ent)[lane]));
    bool sane = (a >= 9.765625e-4f && a <= 64.0f);
    u64 m = __ballot(sane);
    u32 w = ((const u32*)nid)[lane];
    bool oddzero = ((lane & 1) == 0) || (w == 0u);
    u64 m2 = __ballot(oddzero);
    if (lane == 0) {
        flag[0] = (__popcll(m) >= 48) ? 1 : 0;
        flag[1] = (m2 == ~0ull) ? 1 : 0;
    }
}

// K0: convert W + GRU weights/biases to f32 (GRU weights transposed to [K][384]).
__global__ __launch_bounds__(256) void k_prep(
    const void* __restrict__ w_ih, const void* __restrict__ w_hh,
    const void* __restrict__ b_ih, const void* __restrict__ b_hh,
    const void* __restrict__ W, const int* __restrict__ flag,
    float* __restrict__ Wf, float* __restrict__ wTih, float* __restrict__ wThh,
    float* __restrict__ bif, float* __restrict__ bhf)
{
    int isb = flag[0];
    int t = blockIdx.x * 256 + threadIdx.x;
    if (t < 16384) { Wf[t] = ldf(W, t, isb); return; }
    int u = t - 16384;
    if (u < 98304) { int k = u / 384, j = u % 384; wTih[u] = ldf(w_ih, (long)j * 256 + k, isb); return; }
    int v = u - 98304;
    if (v < 49152) { int k = v / 384, j = v % 384; wThh[v] = ldf(w_hh, (long)j * 128 + k, isb); return; }
    int b = v - 49152;
    if (b < 384) { bif[b] = ldf(b_ih, b, isb); return; }
    int c = b - 384;
    if (c < 384) { bhf[c] = ldf(b_hh, c, isb); return; }
}

// K0b: zero the per-node edge counters
__global__ __launch_bounds__(256) void k_zero(int* __restrict__ cnt, int n) {
    int t = blockIdx.x * 256 + threadIdx.x;
    if (t < n) cnt[t] = 0;
}

// K1: hW[n] = ent_embs[node_id[n]] @ W  (4 nodes/block, one wave per node; hW bf16)
__global__ __launch_bounds__(256) void k_gmm(
    const void* __restrict__ ent, const void* __restrict__ node_id,
    const float* __restrict__ Wf, u16* __restrict__ hW,
    const int* __restrict__ flag, int N)
{
    __shared__ float hs[4][D];
    int isb = flag[0], i64 = flag[1];
    int tid = threadIdx.x, r = tid >> 6, lane = tid & 63;
    int n = blockIdx.x * 4 + r;
    if (n < N) {
        long nid = i64 ? (long)((const long long*)node_id)[n]
                       : (long)((const int*)node_id)[n];
        long base2 = nid * (D / 2) + lane;
        if (isb) {
            u32 hv = ((const u32*)ent)[base2];
            hs[r][2 * lane] = bflo(hv); hs[r][2 * lane + 1] = bfhi(hv);
        } else {
            float2 hv = ((const float2*)ent)[base2];
            hs[r][2 * lane] = hv.x; hs[r][2 * lane + 1] = hv.y;
        }
    }
    __syncthreads();
    if (n >= N) return;
    float a0 = 0.f, a1 = 0.f;
    const float2* W2 = (const float2*)Wf;
    #pragma unroll 8
    for (int k = 0; k < D; ++k) {
        float2 w = W2[k * 64 + lane];
        float h = hs[r][k];
        a0 += h * w.x; a1 += h * w.y;
    }
    ((u32*)hW)[(size_t)n * 64 + lane] = ((u32)f2bf(a1) << 16) | (u32)f2bf(a0);
}

// ---- CSR build ----
__global__ __launch_bounds__(256) void k_hist(
    const int* __restrict__ edst, int* __restrict__ cnt, int E)
{
    int e = blockIdx.x * 256 + threadIdx.x;
    if (e < E) atomicAdd(&cnt[edst[e]], 1);
}

// scan pass 1: per-block (1024 elems) exclusive scan + block total
__global__ __launch_bounds__(256) void k_scan1(
    const int* __restrict__ cnt, int* __restrict__ rowstart,
    int* __restrict__ part, int N)
{
    __shared__ int ssum[256];
    int b = blockIdx.x, t = threadIdx.x;
    int base = b * 1024 + t * 4;
    int v[4]; int s = 0;
    #pragma unroll
    for (int i = 0; i < 4; ++i) {
        int idx = base + i;
        v[i] = (idx < N) ? cnt[idx] : 0;
        s += v[i];
    }
    ssum[t] = s;
    __syncthreads();
    #pragma unroll
    for (int off = 1; off < 256; off <<= 1) {
        int x = (t >= off) ? ssum[t - off] : 0;
        __syncthreads();
        ssum[t] += x;
        __syncthreads();
    }
    int run = ssum[t] - s;   // exclusive prefix of this thread's chunk
    #pragma unroll
    for (int i = 0; i < 4; ++i) {
        int idx = base + i;
        if (idx < N) rowstart[idx] = run;
        run += v[i];
    }
    if (t == 255) part[b] = ssum[255];
}

// scan pass 2: serial scan of block totals (tiny)
__global__ __launch_bounds__(64) void k_scan2(
    int* __restrict__ part, int* __restrict__ rowstart, int nb, int N)
{
    if (threadIdx.x == 0) {
        int run = 0;
        for (int b = 0; b < nb; ++b) { int x = part[b]; part[b] = run; run += x; }
        rowstart[N] = run;   // == E
    }
}

// scan pass 3: add block offsets; init cursor (aliased onto cnt)
__global__ __launch_bounds__(256) void k_scan3(
    int* __restrict__ rowstart, const int* __restrict__ part,
    int* __restrict__ cursor, int N)
{
    int t = blockIdx.x * 256 + threadIdx.x;
    if (t < N) {
        int r = rowstart[t] + part[t >> 10];
        rowstart[t] = r;
        cursor[t] = r;
    }
}

// fill: sorted_src[pos] = src for each edge, grouped by dst
__global__ __launch_bounds__(256) void k_fill(
    const int* __restrict__ esrc, const int* __restrict__ edst,
    int* __restrict__ cursor, int* __restrict__ sorted_src, int E)
{
    int e = blockIdx.x * 256 + threadIdx.x;
    if (e < E) {
        int d = edst[e];
        int pos = atomicAdd(&cursor[d], 1);
        sorted_src[pos] = esrc[e];
    }
}

// K3: segment sum — one wave (64 lanes) per node, lane owns 2 dims. No atomics.
__global__ __launch_bounds__(256) void k_seg(
    const u16* __restrict__ hW, const int* __restrict__ rowstart,
    const int* __restrict__ sorted_src, float* __restrict__ agg, int N)
{
    int tid = threadIdx.x;
    int node = blockIdx.x * 4 + (tid >> 6);
    int lane = tid & 63;
    if (node >= N) return;
    int beg = rowstart[node], end = rowstart[node + 1];
    const u32* hw2 = (const u32*)hW;
    float a0 = 0.f, a1 = 0.f;
    int e = beg;
    for (; e + 4 <= end; e += 4) {
        int s0 = sorted_src[e], s1 = sorted_src[e + 1];
        int s2 = sorted_src[e + 2], s3 = sorted_src[e + 3];
        u32 v0 = hw2[(size_t)s0 * 64 + lane];
        u32 v1 = hw2[(size_t)s1 * 64 + lane];
        u32 v2 = hw2[(size_t)s2 * 64 + lane];
        u32 v3 = hw2[(size_t)s3 * 64 + lane];
        a0 += bflo(v0) + bflo(v1) + bflo(v2) + bflo(v3);
        a1 += bfhi(v0) + bfhi(v1) + bfhi(v2) + bfhi(v3);
    }
    for (; e < end; ++e) {
        u32 v = hw2[(size_t)sorted_src[e] * 64 + lane];
        a0 += bflo(v); a1 += bfhi(v);
    }
    ((float2*)agg)[(size_t)node * 64 + lane] = make_float2(a0, a1);
}

// K4: fused GRU + relu + L2-normalize. 8 nodes per 384-thread block.
__global__ __launch_bounds__(384) void k_epi(
    const float* __restrict__ agg, const void* __restrict__ bias,
    const void* __restrict__ onorm, const float* __restrict__ wTih,
    const float* __restrict__ wThh, const float* __restrict__ bif,
    const float* __restrict__ bhf, void* __restrict__ out,
    const int* __restrict__ flag, int N)
{
    __shared__ __align__(16) float xsT[256][8];
    __shared__ float ga[8][384];
    __shared__ float gb[8][384];
    __shared__ float inv8[8];
    int isb = flag[0];
    int tid = threadIdx.x;
    int n0  = blockIdx.x * 8;

    for (int idx = tid; idx < 2048; idx += 384) {
        int n = idx >> 8, k = idx & 255;
        int gn = n0 + n;
        float v = 0.f;
        if (gn < N) {
            if (k < 128) v = agg[(size_t)gn * D + k] * ldf(onorm, gn, isb);
            else         v = ldf(bias, (long)gn * D + (k - 128), isb);
        }
        xsT[k][n] = v;
    }
    __syncthreads();

    {
        int j = tid;
        float ax[8], ah[8];
        #pragma unroll
        for (int n = 0; n < 8; ++n) { ax[n] = 0.f; ah[n] = 0.f; }
        #pragma unroll 4
        for (int k = 0; k < 256; ++k) {
            float w = wTih[k * 384 + j];
            const float4* xp = reinterpret_cast<const float4*>(&xsT[k][0]);
            float4 x0 = xp[0], x1 = xp[1];
            ax[0] += w * x0.x; ax[1] += w * x0.y; ax[2] += w * x0.z; ax[3] += w * x0.w;
            ax[4] += w * x1.x; ax[5] += w * x1.y; ax[6] += w * x1.z; ax[7] += w * x1.w;
        }
        #pragma unroll 4
        for (int k = 0; k < 128; ++k) {
            float w = wThh[k * 384 + j];
            const float4* xp = reinterpret_cast<const float4*>(&xsT[128 + k][0]);
            float4 x0 = xp[0], x1 = xp[1];
            ah[0] += w * x0.x; ah[1] += w * x0.y; ah[2] += w * x0.z; ah[3] += w * x0.w;
            ah[4] += w * x1.x; ah[5] += w * x1.y; ah[6] += w * x1.z; ah[7] += w * x1.w;
        }
        float bi = bif[j], bh = bhf[j];
        #pragma unroll
        for (int n = 0; n < 8; ++n) { ga[n][j] = ax[n] + bi; gb[n][j] = ah[n] + bh; }
    }
    __syncthreads();

    for (int idx = tid; idx < 1024; idx += 384) {
        int n = idx >> 7, dd = idx & 127;
        float r  = sigm(ga[n][dd] + gb[n][dd]);
        float z  = sigm(ga[n][128 + dd] + gb[n][128 + dd]);
        float ng = tanh_fast(ga[n][256 + dd] + r * gb[n][256 + dd]);
        float h  = xsT[128 + dd][n];
        float h0 = (1.f - z) * ng + z * h;
        ga[n][dd] = fmaxf(h0, 0.f);
    }
    __syncthreads();

    if (tid < 256) {
        int n = tid >> 5, l = tid & 31;
        float ss = 0.f;
        #pragma unroll
        for (int i = 0; i < 4; ++i) { float v = ga[n][l + 32 * i]; ss += v * v; }
        #pragma unroll
        for (int off = 16; off >= 1; off >>= 1) ss += __shfl_xor(ss, off, 32);
        if (l == 0) inv8[n] = 1.f / fmaxf(sqrtf(ss), 1e-12f);
    }
    __syncthreads();

    for (int idx = tid; idx < 1024; idx += 384) {
        int n = idx >> 7, dd = idx & 127;
        int gn = n0 + n;
        if (gn < N) {
            float v = ga[n][dd] * inv8[n];
            if (isb) ((u16*)out)[(size_t)gn * D + dd] = f2bf(v);
            else     ((float*)out)[(size_t)gn * D + dd] = v;
        }
    }
}

extern "C" void kernel_launch(void* const* d_in, const int* in_sizes, int n_in,
                              void* d_out, int out_size, void* d_ws, size_t ws_size,
                              hipStream_t stream) {
    const void* ent     = d_in[0];
    const void* bias    = d_in[2];
    const void* onorm   = d_in[3];
    const void* W       = d_in[4];
    const void* w_ih    = d_in[5];
    const void* w_hh    = d_in[6];
    const void* b_ih    = d_in[7];
    const void* b_hh    = d_in[8];
    const void* node_id = d_in[9];
    const int*  esrc    = (const int*)d_in[10];
    const int*  edst    = (const int*)d_in[11];

    int N = in_sizes[2] / D;     // 100000
    int E = in_sizes[10];        // 1600000

    char* ws = (char*)d_ws;
    size_t o = 0;
    int*   flag = (int*)(ws + o);  o += 64;
    float* Wf   = (float*)(ws + o); o += 16384u * 4;
    float* wTih = (float*)(ws + o); o += 98304u * 4;
    float* wThh = (float*)(ws + o); o += 49152u * 4;
    float* bif  = (float*)(ws + o); o += 2048;
    float* bhf  = (float*)(ws + o); o += 2048;
    u16*   hW   = (u16*)(ws + o);   o += (size_t)N * D * 2;
    float* agg  = (float*)(ws + o); o += (size_t)N * D * 4;
    int*   cnt  = (int*)(ws + o);   o += (size_t)N * 4;          // doubles as cursor
    int*   rowstart = (int*)(ws + o); o += ((size_t)N + 16) * 4;
    int*   part = (int*)(ws + o);   o += 4096;
    int*   sorted_src = (int*)(ws + o); o += (size_t)E * 4;
    int*   cursor = cnt;

    int nb = (N + 1023) / 1024;

    k_detect<<<1, 64, 0, stream>>>(ent, node_id, flag);
    k_prep<<<643, 256, 0, stream>>>(w_ih, w_hh, b_ih, b_hh, W, flag,
                                    Wf, wTih, wThh, bif, bhf);
    k_zero<<<(N + 255) / 256, 256, 0, stream>>>(cnt, N);
    k_gmm<<<(N + 3) / 4, 256, 0, stream>>>(ent, node_id, Wf, hW, flag, N);
    k_hist<<<(E + 255) / 256, 256, 0, stream>>>(edst, cnt, E);
    k_scan1<<<nb, 256, 0, stream>>>(cnt, rowstart, part, N);
    k_scan2<<<1, 64, 0, stream>>>(part, rowstart, nb, N);
    k_scan3<<<(N + 255) / 256, 256, 0, stream>>>(rowstart, part, cursor, N);
    k_fill<<<(E + 255) / 256, 256, 0, stream>>>(esrc, edst, cursor, sorted_src, E);
    k_seg<<<(N + 3) / 4, 256, 0, stream>>>(hW, rowstart, sorted_src, agg, N);
    k_epi<<<(N + 7) / 8, 384, 0, stream>>>(agg, bias, onorm, wTih, wThh, bif, bhf,
                                           d_out, flag, N);
}

// Round 4
// 1032.759 us; speedup vs baseline: 3.7181x; 1.3608x over previous
//
#include <hip/hip_runtime.h>
#include <hip/hip_bf16.h>

#define D 128

typedef unsigned short u16;
typedef unsigned int   u32;
typedef unsigned long long u64;
typedef short bf16x8 __attribute__((ext_vector_type(8)));
typedef float f32x4  __attribute__((ext_vector_type(4)));

__device__ __forceinline__ float bf2f(u16 u) {
    union { u32 i; float f; } v; v.i = ((u32)u) << 16; return v.f;
}
__device__ __forceinline__ float bflo(u32 p) {
    union { u32 i; float f; } v; v.i = p << 16; return v.f;
}
__device__ __forceinline__ float bfhi(u32 p) {
    union { u32 i; float f; } v; v.i = p & 0xffff0000u; return v.f;
}
__device__ __forceinline__ u16 f2bf(float f) {
    union { float f; u32 i; } v; v.f = f;
    return (u16)((v.i + 0x7fffu + ((v.i >> 16) & 1u)) >> 16);
}
__device__ __forceinline__ float ldf(const void* p, long i, int isb) {
    return isb ? bf2f(((const u16*)p)[i]) : ((const float*)p)[i];
}

__device__ __forceinline__ float sigm(float x) { return 1.0f / (1.0f + __expf(-x)); }
__device__ __forceinline__ float tanh_fast(float x) {
    float a = fabsf(x);
    float t = __expf(-2.0f * a);
    float r = (1.0f - t) / (1.0f + t);
    return copysignf(r, x);
}

__global__ void DRlocal_net_79173427135059_kernel() {}

// K-1: runtime dtype detection. flag[0]=inputs-are-bf16, flag[1]=node_id-is-int64.
__global__ __launch_bounds__(64) void k_detect(const void* ent, const void* nid, int* flag) {
    int lane = threadIdx.x;
    float a = fabsf(bf2f(((const u16*)ent)[lane]));
    bool sane = (a >= 9.765625e-4f && a <= 64.0f);
    u64 m = __ballot(sane);
    u32 w = ((const u32*)nid)[lane];
    bool oddzero = ((lane & 1) == 0) || (w == 0u);
    u64 m2 = __ballot(oddzero);
    if (lane == 0) {
        flag[0] = (__popcll(m) >= 48) ? 1 : 0;
        flag[1] = (m2 == ~0ull) ? 1 : 0;
    }
}

// K0: weights -> bf16 (as-is layout: Wih [384,256], Whh [384,128]); biases -> f32.
__global__ __launch_bounds__(256) void k_prep(
    const void* __restrict__ w_ih, const void* __restrict__ w_hh,
    const void* __restrict__ b_ih, const void* __restrict__ b_hh,
    const void* __restrict__ W, const int* __restrict__ flag,
    float* __restrict__ Wf, u16* __restrict__ Wihb, u16* __restrict__ Whhb,
    float* __restrict__ bif, float* __restrict__ bhf)
{
    int isb = flag[0];
    int t = blockIdx.x * 256 + threadIdx.x;
    if (t < 16384) { Wf[t] = ldf(W, t, isb); return; }
    int u = t - 16384;
    if (u < 98304) { Wihb[u] = isb ? ((const u16*)w_ih)[u] : f2bf(((const float*)w_ih)[u]); return; }
    int v = u - 98304;
    if (v < 49152) { Whhb[v] = isb ? ((const u16*)w_hh)[v] : f2bf(((const float*)w_hh)[v]); return; }
    int b = v - 49152;
    if (b < 384) { bif[b] = ldf(b_ih, b, isb); return; }
    int c = b - 384;
    if (c < 384) { bhf[c] = ldf(b_hh, c, isb); return; }
}

__global__ __launch_bounds__(256) void k_zero(int* __restrict__ cnt, int n) {
    int t = blockIdx.x * 256 + threadIdx.x;
    if (t < n) cnt[t] = 0;
}

// K1: hW[n] = ent_embs[node_id[n]] @ W  (4 nodes/block, one wave per node; hW bf16)
__global__ __launch_bounds__(256) void k_gmm(
    const void* __restrict__ ent, const void* __restrict__ node_id,
    const float* __restrict__ Wf, u16* __restrict__ hW,
    const int* __restrict__ flag, int N)
{
    __shared__ float hs[4][D];
    int isb = flag[0], i64 = flag[1];
    int tid = threadIdx.x, r = tid >> 6, lane = tid & 63;
    int n = blockIdx.x * 4 + r;
    if (n < N) {
        long nid = i64 ? (long)((const long long*)node_id)[n]
                       : (long)((const int*)node_id)[n];
        long base2 = nid * (D / 2) + lane;
        if (isb) {
            u32 hv = ((const u32*)ent)[base2];
            hs[r][2 * lane] = bflo(hv); hs[r][2 * lane + 1] = bfhi(hv);
        } else {
            float2 hv = ((const float2*)ent)[base2];
            hs[r][2 * lane] = hv.x; hs[r][2 * lane + 1] = hv.y;
        }
    }
    __syncthreads();
    if (n >= N) return;
    float a0 = 0.f, a1 = 0.f;
    const float2* W2 = (const float2*)Wf;
    #pragma unroll 8
    for (int k = 0; k < D; ++k) {
        float2 w = W2[k * 64 + lane];
        float h = hs[r][k];
        a0 += h * w.x; a1 += h * w.y;
    }
    ((u32*)hW)[(size_t)n * 64 + lane] = ((u32)f2bf(a1) << 16) | (u32)f2bf(a0);
}

// ---- CSR build ----
__global__ __launch_bounds__(256) void k_hist(
    const int* __restrict__ edst, int* __restrict__ cnt, int E)
{
    int e = blockIdx.x * 256 + threadIdx.x;
    if (e < E) atomicAdd(&cnt[edst[e]], 1);
}

__global__ __launch_bounds__(256) void k_scan1(
    const int* __restrict__ cnt, int* __restrict__ rowstart,
    int* __restrict__ part, int N)
{
    __shared__ int ssum[256];
    int b = blockIdx.x, t = threadIdx.x;
    int base = b * 1024 + t * 4;
    int v[4]; int s = 0;
    #pragma unroll
    for (int i = 0; i < 4; ++i) {
        int idx = base + i;
        v[i] = (idx < N) ? cnt[idx] : 0;
        s += v[i];
    }
    ssum[t] = s;
    __syncthreads();
    #pragma unroll
    for (int off = 1; off < 256; off <<= 1) {
        int x = (t >= off) ? ssum[t - off] : 0;
        __syncthreads();
        ssum[t] += x;
        __syncthreads();
    }
    int run = ssum[t] - s;
    #pragma unroll
    for (int i = 0; i < 4; ++i) {
        int idx = base + i;
        if (idx < N) rowstart[idx] = run;
        run += v[i];
    }
    if (t == 255) part[b] = ssum[255];
}

__global__ __launch_bounds__(64) void k_scan2(
    int* __restrict__ part, int* __restrict__ rowstart, int nb, int N)
{
    if (threadIdx.x == 0) {
        int run = 0;
        for (int b = 0; b < nb; ++b) { int x = part[b]; part[b] = run; run += x; }
        rowstart[N] = run;
    }
}

__global__ __launch_bounds__(256) void k_scan3(
    int* __restrict__ rowstart, const int* __restrict__ part,
    int* __restrict__ cursor, int N)
{
    int t = blockIdx.x * 256 + threadIdx.x;
    if (t < N) {
        int r = rowstart[t] + part[t >> 10];
        rowstart[t] = r;
        cursor[t] = r;
    }
}

__global__ __launch_bounds__(256) void k_fill(
    const int* __restrict__ esrc, const int* __restrict__ edst,
    int* __restrict__ cursor, int* __restrict__ sorted_src, int E)
{
    int e = blockIdx.x * 256 + threadIdx.x;
    if (e < E) {
        int d = edst[e];
        int pos = atomicAdd(&cursor[d], 1);
        sorted_src[pos] = esrc[e];
    }
}

// K3: segment sum -> X[:,0:128] = bf16(agg * out_norm). One wave per node.
__global__ __launch_bounds__(256) void k_seg(
    const u16* __restrict__ hW, const int* __restrict__ rowstart,
    const int* __restrict__ sorted_src, const void* __restrict__ onorm,
    u16* __restrict__ X, const int* __restrict__ flag, int N)
{
    int isb = flag[0];
    int tid = threadIdx.x;
    int node = blockIdx.x * 4 + (tid >> 6);
    int lane = tid & 63;
    if (node >= N) return;
    int beg = rowstart[node], end = rowstart[node + 1];
    const u32* hw2 = (const u32*)hW;
    float a0 = 0.f, a1 = 0.f;
    int e = beg;
    for (; e + 4 <= end; e += 4) {
        int s0 = sorted_src[e], s1 = sorted_src[e + 1];
        int s2 = sorted_src[e + 2], s3 = sorted_src[e + 3];
        u32 v0 = hw2[(size_t)s0 * 64 + lane];
        u32 v1 = hw2[(size_t)s1 * 64 + lane];
        u32 v2 = hw2[(size_t)s2 * 64 + lane];
        u32 v3 = hw2[(size_t)s3 * 64 + lane];
        a0 += bflo(v0) + bflo(v1) + bflo(v2) + bflo(v3);
        a1 += bfhi(v0) + bfhi(v1) + bfhi(v2) + bfhi(v3);
    }
    for (; e < end; ++e) {
        u32 v = hw2[(size_t)sorted_src[e] * 64 + lane];
        a0 += bflo(v); a1 += bfhi(v);
    }
    float on = ldf(onorm, node, isb);
    u32 p = ((u32)f2bf(a1 * on) << 16) | (u32)f2bf(a0 * on);
    ((u32*)X)[(size_t)node * 128 + lane] = p;   // X row stride 256 bf16 = 128 u32
}

// K3b: X[:,128:256] = e_r_bias (bf16)
__global__ __launch_bounds__(256) void k_copybias(
    const void* __restrict__ bias, u16* __restrict__ X,
    const int* __restrict__ flag, int N)
{
    int isb = flag[0];
    int t = blockIdx.x * 256 + threadIdx.x;   // over N*64 u32 words
    if (t >= N * 64) return;
    int row = t >> 6, c2 = t & 63;
    u32 p;
    if (isb) p = ((const u32*)bias)[(size_t)row * 64 + c2];
    else {
        const float* bp = (const float*)bias + (size_t)row * 128 + c2 * 2;
        p = ((u32)f2bf(bp[1]) << 16) | (u32)f2bf(bp[0]);
    }
    ((u32*)X)[(size_t)row * 128 + 64 + c2] = p;
}

// K4: MFMA GRU: ga = X @ Wih^T, gb = X[:,128:] @ Whh^T, then gates+relu+L2norm.
// Block: 32 rows, 4 waves x 96 cols. A/B frags: row-major [m][k], lane m=l&15, k=(l>>4)*8+j.
// C frag: col n=l&15, row m=(l>>4)*4+reg.
__global__ __launch_bounds__(256) void k_gru_mfma(
    const u16* __restrict__ X, const u16* __restrict__ Wih,
    const u16* __restrict__ Whh, const float* __restrict__ bif,
    const float* __restrict__ bhf, void* __restrict__ out,
    const int* __restrict__ flag, int N)
{
    __shared__ float lga[384][33];   // [col][row], stride 33: gate reads conflict-free
    __shared__ float lgb[384][33];
    __shared__ float h0s[32][132];
    __shared__ float invs[32];
    int isb = flag[0];
    int tid = threadIdx.x;
    int wave = tid >> 6, lane = tid & 63;
    int row0 = blockIdx.x * 32;
    int col0 = wave * 96;
    int qm = lane >> 4, qr = lane & 15;

    // A-fragments: a[ms][s] = X[row0+ms*16+qr][s*32 + qm*8 .. +8]
    bf16x8 a[2][8];
    const u16* xb = X + (size_t)(row0 + qr) * 256 + qm * 8;
    #pragma unroll
    for (int ms = 0; ms < 2; ++ms)
        #pragma unroll
        for (int s = 0; s < 8; ++s)
            a[ms][s] = *(const bf16x8*)(xb + (size_t)ms * 16 * 256 + s * 32);

    f32x4 accA[2][6], accB[2][6];
    f32x4 zz = {0.f, 0.f, 0.f, 0.f};
    #pragma unroll
    for (int ms = 0; ms < 2; ++ms)
        #pragma unroll
        for (int f = 0; f < 6; ++f) { accA[ms][f] = zz; accB[ms][f] = zz; }

    // ga chain: K=256 over Wih
    #pragma unroll
    for (int f = 0; f < 6; ++f) {
        const u16* wp = Wih + (size_t)(col0 + f * 16 + qr) * 256 + qm * 8;
        #pragma unroll
        for (int s = 0; s < 8; ++s) {
            bf16x8 b = *(const bf16x8*)(wp + s * 32);
            accA[0][f] = __builtin_amdgcn_mfma_f32_16x16x32_bf16(a[0][s], b, accA[0][f], 0, 0, 0);
            accA[1][f] = __builtin_amdgcn_mfma_f32_16x16x32_bf16(a[1][s], b, accA[1][f], 0, 0, 0);
        }
    }
    // gb chain: K=128 over Whh; A-frags are X cols 128..255 = a[ms][4+s]
    #pragma unroll
    for (int f = 0; f < 6; ++f) {
        const u16* wp = Whh + (size_t)(col0 + f * 16 + qr) * 128 + qm * 8;
        #pragma unroll
        for (int s = 0; s < 4; ++s) {
            bf16x8 b = *(const bf16x8*)(wp + s * 32);
            accB[0][f] = __builtin_amdgcn_mfma_f32_16x16x32_bf16(a[0][4 + s], b, accB[0][f], 0, 0, 0);
            accB[1][f] = __builtin_amdgcn_mfma_f32_16x16x32_bf16(a[1][4 + s], b, accB[1][f], 0, 0, 0);
        }
    }

    // write accums (+bias) to LDS, column-major
    #pragma unroll
    for (int f = 0; f < 6; ++f) {
        int n = col0 + f * 16 + qr;
        float bi = bif[n], bh = bhf[n];
        #pragma unroll
        for (int ms = 0; ms < 2; ++ms) {
            int m0 = ms * 16 + qm * 4;
            #pragma unroll
            for (int r = 0; r < 4; ++r) {
                lga[n][m0 + r] = accA[ms][f][r] + bi;
                lgb[n][m0 + r] = accB[ms][f][r] + bh;
            }
        }
    }
    __syncthreads();

    // gates + relu
    #pragma unroll 4
    for (int it = 0; it < 16; ++it) {
        int idx = tid + it * 256;
        int row = idx >> 7, j = idx & 127;
        float xr = lga[j][row],       hr = lgb[j][row];
        float xz = lga[128 + j][row], hz = lgb[128 + j][row];
        float xn = lga[256 + j][row], hn = lgb[256 + j][row];
        float r = sigm(xr + hr);
        float z = sigm(xz + hz);
        float ng = tanh_fast(xn + r * hn);
        float h  = bf2f(X[(size_t)(row0 + row) * 256 + 128 + j]);
        float h0 = (1.f - z) * ng + z * h;
        h0s[row][j] = fmaxf(h0, 0.f);
    }
    __syncthreads();

    // per-row L2 norm: 8 threads/row
    {
        int node = tid >> 3, l = tid & 7;
        float ss = 0.f;
        #pragma unroll
        for (int i = 0; i < 16; ++i) { float v = h0s[node][l * 16 + i]; ss += v * v; }
        ss += __shfl_xor(ss, 1, 64);
        ss += __shfl_xor(ss, 2, 64);
        ss += __shfl_xor(ss, 4, 64);
        if (l == 0) invs[node] = 1.f / fmaxf(sqrtf(ss), 1e-12f);
    }
    __syncthreads();

    // scale + store
    #pragma unroll 4
    for (int it = 0; it < 16; ++it) {
        int idx = tid + it * 256;
        int row = idx >> 7, j = idx & 127;
        int gn = row0 + row;
        if (gn < N) {
            float v = h0s[row][j] * invs[row];
            if (isb) ((u16*)out)[(size_t)gn * 128 + j] = f2bf(v);
            else     ((float*)out)[(size_t)gn * 128 + j] = v;
        }
    }
}

extern "C" void kernel_launch(void* const* d_in, const int* in_sizes, int n_in,
                              void* d_out, int out_size, void* d_ws, size_t ws_size,
                              hipStream_t stream) {
    const void* ent     = d_in[0];
    const void* bias    = d_in[2];
    const void* onorm   = d_in[3];
    const void* W       = d_in[4];
    const void* w_ih    = d_in[5];
    const void* w_hh    = d_in[6];
    const void* b_ih    = d_in[7];
    const void* b_hh    = d_in[8];
    const void* node_id = d_in[9];
    const int*  esrc    = (const int*)d_in[10];
    const int*  edst    = (const int*)d_in[11];

    int N = in_sizes[2] / D;     // 100000
    int E = in_sizes[10];        // 1600000
    int Npad = ((N + 31) / 32) * 32;

    char* ws = (char*)d_ws;
    size_t o = 0;
    int*   flag = (int*)(ws + o);   o += 64;
    float* Wf   = (float*)(ws + o); o += 16384u * 4;
    u16*   Wihb = (u16*)(ws + o);   o += 98304u * 2;
    u16*   Whhb = (u16*)(ws + o);   o += 49152u * 2;
    float* bif  = (float*)(ws + o); o += 2048;
    float* bhf  = (float*)(ws + o); o += 2048;
    u16*   X    = (u16*)(ws + o);   o += (size_t)Npad * 256 * 2;   // [Npad,256] bf16
    u16*   hW   = (u16*)(ws + o);   o += (size_t)N * D * 2;
    int*   cnt  = (int*)(ws + o);   o += (size_t)N * 4;            // doubles as cursor
    int*   rowstart = (int*)(ws + o); o += ((size_t)N + 16) * 4;
    int*   part = (int*)(ws + o);   o += 4096;
    int*   sorted_src = (int*)(ws + o); o += (size_t)E * 4;
    int*   cursor = cnt;

    int nb = (N + 1023) / 1024;

    k_detect<<<1, 64, 0, stream>>>(ent, node_id, flag);
    k_prep<<<643, 256, 0, stream>>>(w_ih, w_hh, b_ih, b_hh, W, flag,
                                    Wf, Wihb, Whhb, bif, bhf);
    k_zero<<<(N + 255) / 256, 256, 0, stream>>>(cnt, N);
    k_gmm<<<(N + 3) / 4, 256, 0, stream>>>(ent, node_id, Wf, hW, flag, N);
    k_hist<<<(E + 255) / 256, 256, 0, stream>>>(edst, cnt, E);
    k_scan1<<<nb, 256, 0, stream>>>(cnt, rowstart, part, N);
    k_scan2<<<1, 64, 0, stream>>>(part, rowstart, nb, N);
    k_scan3<<<(N + 255) / 256, 256, 0, stream>>>(rowstart, part, cursor, N);
    k_fill<<<(E + 255) / 256, 256, 0, stream>>>(esrc, edst, cursor, sorted_src, E);
    k_seg<<<(N + 3) / 4, 256, 0, stream>>>(hW, rowstart, sorted_src, onorm, X, flag, N);
    k_copybias<<<(N * 64 + 255) / 256, 256, 0, stream>>>(bias, X, flag, N);
    k_gru_mfma<<<Npad / 32, 256, 0, stream>>>(X, Wihb, Whhb, bif, bhf, d_out, flag, N);
}

// Round 5
// 723.730 us; speedup vs baseline: 5.3057x; 1.4270x over previous
//
#include <hip/hip_runtime.h>
#include <hip/hip_bf16.h>

#define D 128

typedef unsigned short u16;
typedef unsigned int   u32;
typedef unsigned long long u64;
typedef short bf16x8 __attribute__((ext_vector_type(8)));
typedef float f32x4  __attribute__((ext_vector_type(4)));

__device__ __forceinline__ float bf2f(u16 u) {
    union { u32 i; float f; } v; v.i = ((u32)u) << 16; return v.f;
}
__device__ __forceinline__ float bflo(u32 p) {
    union { u32 i; float f; } v; v.i = p << 16; return v.f;
}
__device__ __forceinline__ float bfhi(u32 p) {
    union { u32 i; float f; } v; v.i = p & 0xffff0000u; return v.f;
}
__device__ __forceinline__ u16 f2bf(float f) {
    union { float f; u32 i; } v; v.f = f;
    return (u16)((v.i + 0x7fffu + ((v.i >> 16) & 1u)) >> 16);
}
__device__ __forceinline__ float ldf(const void* p, long i, int isb) {
    return isb ? bf2f(((const u16*)p)[i]) : ((const float*)p)[i];
}

__device__ __forceinline__ float sigm(float x) { return 1.0f / (1.0f + __expf(-x)); }
__device__ __forceinline__ float tanh_fast(float x) {
    float a = fabsf(x);
    float t = __expf(-2.0f * a);
    float r = (1.0f - t) / (1.0f + t);
    return copysignf(r, x);
}

__global__ void DRlocal_net_79173427135059_kernel() {}

// K-1: runtime dtype detection. flag[0]=inputs-are-bf16, flag[1]=node_id-is-int64.
__global__ __launch_bounds__(64) void k_detect(const void* ent, const void* nid, int* flag) {
    int lane = threadIdx.x;
    float a = fabsf(bf2f(((const u16*)ent)[lane]));
    bool sane = (a >= 9.765625e-4f && a <= 64.0f);
    u64 m = __ballot(sane);
    u32 w = ((const u32*)nid)[lane];
    bool oddzero = ((lane & 1) == 0) || (w == 0u);
    u64 m2 = __ballot(oddzero);
    if (lane == 0) {
        flag[0] = (__popcll(m) >= 48) ? 1 : 0;
        flag[1] = (m2 == ~0ull) ? 1 : 0;
    }
}

// K0: WTb[j][k] = bf16(W[k][j]); GRU weights -> bf16 as-is; biases -> f32.
__global__ __launch_bounds__(256) void k_prep(
    const void* __restrict__ w_ih, const void* __restrict__ w_hh,
    const void* __restrict__ b_ih, const void* __restrict__ b_hh,
    const void* __restrict__ W, const int* __restrict__ flag,
    u16* __restrict__ WTb, u16* __restrict__ Wihb, u16* __restrict__ Whhb,
    float* __restrict__ bif, float* __restrict__ bhf)
{
    int isb = flag[0];
    int t = blockIdx.x * 256 + threadIdx.x;
    if (t < 16384) {
        int k = t >> 7, j = t & 127;
        u16 v = isb ? ((const u16*)W)[t] : f2bf(((const float*)W)[t]);
        WTb[j * 128 + k] = v;
        return;
    }
    int u = t - 16384;
    if (u < 98304) { Wihb[u] = isb ? ((const u16*)w_ih)[u] : f2bf(((const float*)w_ih)[u]); return; }
    int v = u - 98304;
    if (v < 49152) { Whhb[v] = isb ? ((const u16*)w_hh)[v] : f2bf(((const float*)w_hh)[v]); return; }
    int b = v - 49152;
    if (b < 384) { bif[b] = ldf(b_ih, b, isb); return; }
    int c = b - 384;
    if (c < 384) { bhf[c] = ldf(b_hh, c, isb); return; }
}

__global__ __launch_bounds__(256) void k_zero(int* __restrict__ cnt, int n) {
    int t = blockIdx.x * 256 + threadIdx.x;
    if (t < n) cnt[t] = 0;
}

// K1: hW = gather(ent, node_id) @ W via MFMA. 64 nodes/block, wave = one 16-row m-tile.
// A-frags gathered straight to registers; B = WTb rows (L1-resident).
__global__ __launch_bounds__(256) void k_gmm_mfma(
    const void* __restrict__ ent, const void* __restrict__ node_id,
    const u16* __restrict__ WTb, u16* __restrict__ hW,
    const int* __restrict__ flag, int N)
{
    int isb = flag[0], i64 = flag[1];
    int tid = threadIdx.x;
    int wave = tid >> 6, lane = tid & 63;
    int qm = lane >> 4, qr = lane & 15;
    int row0 = blockIdx.x * 64 + wave * 16;

    int rowA = row0 + qr; if (rowA >= N) rowA = N - 1;
    long nid = i64 ? (long)((const long long*)node_id)[rowA]
                   : (long)((const int*)node_id)[rowA];

    // A[m=qr][k = s*32 + qm*8 + j]
    bf16x8 a[4];
    if (isb) {
        const u16* ep = (const u16*)ent + nid * 128 + qm * 8;
        #pragma unroll
        for (int s = 0; s < 4; ++s) a[s] = *(const bf16x8*)(ep + s * 32);
    } else {
        const float* ep = (const float*)ent + nid * 128 + qm * 8;
        #pragma unroll
        for (int s = 0; s < 4; ++s) {
            float4 f0 = *(const float4*)(ep + s * 32);
            float4 f1 = *(const float4*)(ep + s * 32 + 4);
            bf16x8 t;
            t[0] = (short)f2bf(f0.x); t[1] = (short)f2bf(f0.y);
            t[2] = (short)f2bf(f0.z); t[3] = (short)f2bf(f0.w);
            t[4] = (short)f2bf(f1.x); t[5] = (short)f2bf(f1.y);
            t[6] = (short)f2bf(f1.z); t[7] = (short)f2bf(f1.w);
            a[s] = t;
        }
    }

    int r0 = row0 + qm * 4;
    #pragma unroll
    for (int f = 0; f < 8; ++f) {
        f32x4 acc = {0.f, 0.f, 0.f, 0.f};
        const u16* wp = WTb + (size_t)(f * 16 + qr) * 128 + qm * 8;
        #pragma unroll
        for (int s = 0; s < 4; ++s) {
            bf16x8 b = *(const bf16x8*)(wp + s * 32);
            acc = __builtin_amdgcn_mfma_f32_16x16x32_bf16(a[s], b, acc, 0, 0, 0);
        }
        int col = f * 16 + qr;
        #pragma unroll
        for (int r = 0; r < 4; ++r) {
            int row = r0 + r;
            if (row < N) hW[(size_t)row * 128 + col] = f2bf(acc[r]);
        }
    }
}

// ---- CSR build ----
__global__ __launch_bounds__(256) void k_hist(
    const int* __restrict__ edst, int* __restrict__ cnt, int E)
{
    int e = blockIdx.x * 256 + threadIdx.x;
    if (e < E) atomicAdd(&cnt[edst[e]], 1);
}

__global__ __launch_bounds__(256) void k_scan1(
    const int* __restrict__ cnt, int* __restrict__ rowstart,
    int* __restrict__ part, int N)
{
    __shared__ int ssum[256];
    int b = blockIdx.x, t = threadIdx.x;
    int base = b * 1024 + t * 4;
    int v[4]; int s = 0;
    #pragma unroll
    for (int i = 0; i < 4; ++i) {
        int idx = base + i;
        v[i] = (idx < N) ? cnt[idx] : 0;
        s += v[i];
    }
    ssum[t] = s;
    __syncthreads();
    #pragma unroll
    for (int off = 1; off < 256; off <<= 1) {
        int x = (t >= off) ? ssum[t - off] : 0;
        __syncthreads();
        ssum[t] += x;
        __syncthreads();
    }
    int run = ssum[t] - s;
    #pragma unroll
    for (int i = 0; i < 4; ++i) {
        int idx = base + i;
        if (idx < N) rowstart[idx] = run;
        run += v[i];
    }
    if (t == 255) part[b] = ssum[255];
}

__global__ __launch_bounds__(64) void k_scan2(
    int* __restrict__ part, int* __restrict__ rowstart, int nb, int N)
{
    if (threadIdx.x == 0) {
        int run = 0;
        for (int b = 0; b < nb; ++b) { int x = part[b]; part[b] = run; run += x; }
        rowstart[N] = run;
    }
}

__global__ __launch_bounds__(256) void k_scan3(
    int* __restrict__ rowstart, const int* __restrict__ part,
    int* __restrict__ cursor, int N)
{
    int t = blockIdx.x * 256 + threadIdx.x;
    if (t < N) {
        int r = rowstart[t] + part[t >> 10];
        rowstart[t] = r;
        cursor[t] = r;
    }
}

__global__ __launch_bounds__(256) void k_fill(
    const int* __restrict__ esrc, const int* __restrict__ edst,
    int* __restrict__ cursor, int* __restrict__ sorted_src, int E)
{
    int e = blockIdx.x * 256 + threadIdx.x;
    if (e < E) {
        int d = edst[e];
        int pos = atomicAdd(&cursor[d], 1);
        sorted_src[pos] = esrc[e];
    }
}

// K3: segment sum -> X[:,0:128] = bf16(agg*out_norm); also X[:,128:256] = e_r_bias.
__global__ __launch_bounds__(256) void k_seg(
    const u16* __restrict__ hW, const int* __restrict__ rowstart,
    const int* __restrict__ sorted_src, const void* __restrict__ onorm,
    const void* __restrict__ bias, u16* __restrict__ X,
    const int* __restrict__ flag, int N)
{
    int isb = flag[0];
    int tid = threadIdx.x;
    int node = blockIdx.x * 4 + (tid >> 6);
    int lane = tid & 63;
    if (node >= N) return;
    int beg = rowstart[node], end = rowstart[node + 1];
    const u32* hw2 = (const u32*)hW;
    float a0 = 0.f, a1 = 0.f;
    int e = beg;
    for (; e + 4 <= end; e += 4) {
        int s0 = sorted_src[e], s1 = sorted_src[e + 1];
        int s2 = sorted_src[e + 2], s3 = sorted_src[e + 3];
        u32 v0 = hw2[(size_t)s0 * 64 + lane];
        u32 v1 = hw2[(size_t)s1 * 64 + lane];
        u32 v2 = hw2[(size_t)s2 * 64 + lane];
        u32 v3 = hw2[(size_t)s3 * 64 + lane];
        a0 += bflo(v0) + bflo(v1) + bflo(v2) + bflo(v3);
        a1 += bfhi(v0) + bfhi(v1) + bfhi(v2) + bfhi(v3);
    }
    for (; e < end; ++e) {
        u32 v = hw2[(size_t)sorted_src[e] * 64 + lane];
        a0 += bflo(v); a1 += bfhi(v);
    }
    float on = ldf(onorm, node, isb);
    u32 p = ((u32)f2bf(a1 * on) << 16) | (u32)f2bf(a0 * on);
    ((u32*)X)[(size_t)node * 128 + lane] = p;
    // bias half
    u32 pb;
    if (isb) pb = ((const u32*)bias)[(size_t)node * 64 + lane];
    else {
        const float* bp = (const float*)bias + (size_t)node * 128 + lane * 2;
        pb = ((u32)f2bf(bp[1]) << 16) | (u32)f2bf(bp[0]);
    }
    ((u32*)X)[(size_t)node * 128 + 64 + lane] = pb;
}

// K4: MFMA GRU: ga = X @ Wih^T, gb = X[:,128:] @ Whh^T, then gates+relu+L2norm.
__global__ __launch_bounds__(256) void k_gru_mfma(
    const u16* __restrict__ X, const u16* __restrict__ Wih,
    const u16* __restrict__ Whh, const float* __restrict__ bif,
    const float* __restrict__ bhf, void* __restrict__ out,
    const int* __restrict__ flag, int N)
{
    __shared__ float lga[384][33];
    __shared__ float lgb[384][33];
    __shared__ float h0s[32][132];
    __shared__ float invs[32];
    int isb = flag[0];
    int tid = threadIdx.x;
    int wave = tid >> 6, lane = tid & 63;
    int row0 = blockIdx.x * 32;
    int col0 = wave * 96;
    int qm = lane >> 4, qr = lane & 15;

    bf16x8 a[2][8];
    const u16* xb = X + (size_t)(row0 + qr) * 256 + qm * 8;
    #pragma unroll
    for (int ms = 0; ms < 2; ++ms)
        #pragma unroll
        for (int s = 0; s < 8; ++s)
            a[ms][s] = *(const bf16x8*)(xb + (size_t)ms * 16 * 256 + s * 32);

    f32x4 accA[2][6], accB[2][6];
    f32x4 zz = {0.f, 0.f, 0.f, 0.f};
    #pragma unroll
    for (int ms = 0; ms < 2; ++ms)
        #pragma unroll
        for (int f = 0; f < 6; ++f) { accA[ms][f] = zz; accB[ms][f] = zz; }

    #pragma unroll
    for (int f = 0; f < 6; ++f) {
        const u16* wp = Wih + (size_t)(col0 + f * 16 + qr) * 256 + qm * 8;
        #pragma unroll
        for (int s = 0; s < 8; ++s) {
            bf16x8 b = *(const bf16x8*)(wp + s * 32);
            accA[0][f] = __builtin_amdgcn_mfma_f32_16x16x32_bf16(a[0][s], b, accA[0][f], 0, 0, 0);
            accA[1][f] = __builtin_amdgcn_mfma_f32_16x16x32_bf16(a[1][s], b, accA[1][f], 0, 0, 0);
        }
    }
    #pragma unroll
    for (int f = 0; f < 6; ++f) {
        const u16* wp = Whh + (size_t)(col0 + f * 16 + qr) * 128 + qm * 8;
        #pragma unroll
        for (int s = 0; s < 4; ++s) {
            bf16x8 b = *(const bf16x8*)(wp + s * 32);
            accB[0][f] = __builtin_amdgcn_mfma_f32_16x16x32_bf16(a[0][4 + s], b, accB[0][f], 0, 0, 0);
            accB[1][f] = __builtin_amdgcn_mfma_f32_16x16x32_bf16(a[1][4 + s], b, accB[1][f], 0, 0, 0);
        }
    }

    #pragma unroll
    for (int f = 0; f < 6; ++f) {
        int n = col0 + f * 16 + qr;
        float bi = bif[n], bh = bhf[n];
        #pragma unroll
        for (int ms = 0; ms < 2; ++ms) {
            int m0 = ms * 16 + qm * 4;
            #pragma unroll
            for (int r = 0; r < 4; ++r) {
                lga[n][m0 + r] = accA[ms][f][r] + bi;
                lgb[n][m0 + r] = accB[ms][f][r] + bh;
            }
        }
    }
    __syncthreads();

    #pragma unroll 4
    for (int it = 0; it < 16; ++it) {
        int idx = tid + it * 256;
        int row = idx >> 7, j = idx & 127;
        float xr = lga[j][row],       hr = lgb[j][row];
        float xz = lga[128 + j][row], hz = lgb[128 + j][row];
        float xn = lga[256 + j][row], hn = lgb[256 + j][row];
        float r = sigm(xr + hr);
        float z = sigm(xz + hz);
        float ng = tanh_fast(xn + r * hn);
        float h  = bf2f(X[(size_t)(row0 + row) * 256 + 128 + j]);
        float h0 = (1.f - z) * ng + z * h;
        h0s[row][j] = fmaxf(h0, 0.f);
    }
    __syncthreads();

    {
        int node = tid >> 3, l = tid & 7;
        float ss = 0.f;
        #pragma unroll
        for (int i = 0; i < 16; ++i) { float v = h0s[node][l * 16 + i]; ss += v * v; }
        ss += __shfl_xor(ss, 1, 64);
        ss += __shfl_xor(ss, 2, 64);
        ss += __shfl_xor(ss, 4, 64);
        if (l == 0) invs[node] = 1.f / fmaxf(sqrtf(ss), 1e-12f);
    }
    __syncthreads();

    #pragma unroll 4
    for (int it = 0; it < 16; ++it) {
        int idx = tid + it * 256;
        int row = idx >> 7, j = idx & 127;
        int gn = row0 + row;
        if (gn < N) {
            float v = h0s[row][j] * invs[row];
            if (isb) ((u16*)out)[(size_t)gn * 128 + j] = f2bf(v);
            else     ((float*)out)[(size_t)gn * 128 + j] = v;
        }
    }
}

extern "C" void kernel_launch(void* const* d_in, const int* in_sizes, int n_in,
                              void* d_out, int out_size, void* d_ws, size_t ws_size,
                              hipStream_t stream) {
    const void* ent     = d_in[0];
    const void* bias    = d_in[2];
    const void* onorm   = d_in[3];
    const void* W       = d_in[4];
    const void* w_ih    = d_in[5];
    const void* w_hh    = d_in[6];
    const void* b_ih    = d_in[7];
    const void* b_hh    = d_in[8];
    const void* node_id = d_in[9];
    const int*  esrc    = (const int*)d_in[10];
    const int*  edst    = (const int*)d_in[11];

    int N = in_sizes[2] / D;     // 100000
    int E = in_sizes[10];        // 1600000
    int Npad = ((N + 31) / 32) * 32;

    char* ws = (char*)d_ws;
    size_t o = 0;
    int*   flag = (int*)(ws + o);   o += 64;
    u16*   WTb  = (u16*)(ws + o);   o += 16384u * 2;
    u16*   Wihb = (u16*)(ws + o);   o += 98304u * 2;
    u16*   Whhb = (u16*)(ws + o);   o += 49152u * 2;
    float* bif  = (float*)(ws + o); o += 2048;
    float* bhf  = (float*)(ws + o); o += 2048;
    u16*   X    = (u16*)(ws + o);   o += (size_t)Npad * 256 * 2;
    u16*   hW   = (u16*)(ws + o);   o += (size_t)N * D * 2;
    int*   cnt  = (int*)(ws + o);   o += (size_t)N * 4;
    int*   rowstart = (int*)(ws + o); o += ((size_t)N + 16) * 4;
    int*   part = (int*)(ws + o);   o += 4096;
    int*   sorted_src = (int*)(ws + o); o += (size_t)E * 4;
    int*   cursor = cnt;

    int nb = (N + 1023) / 1024;

    k_detect<<<1, 64, 0, stream>>>(ent, node_id, flag);
    k_prep<<<643, 256, 0, stream>>>(w_ih, w_hh, b_ih, b_hh, W, flag,
                                    WTb, Wihb, Whhb, bif, bhf);
    k_zero<<<(N + 255) / 256, 256, 0, stream>>>(cnt, N);
    k_gmm_mfma<<<(N + 63) / 64, 256, 0, stream>>>(ent, node_id, WTb, hW, flag, N);
    k_hist<<<(E + 255) / 256, 256, 0, stream>>>(edst, cnt, E);
    k_scan1<<<nb, 256, 0, stream>>>(cnt, rowstart, part, N);
    k_scan2<<<1, 64, 0, stream>>>(part, rowstart, nb, N);
    k_scan3<<<(N + 255) / 256, 256, 0, stream>>>(rowstart, part, cursor, N);
    k_fill<<<(E + 255) / 256, 256, 0, stream>>>(esrc, edst, cursor, sorted_src, E);
    k_seg<<<(N + 3) / 4, 256, 0, stream>>>(hW, rowstart, sorted_src, onorm, bias, X, flag, N);
    k_gru_mfma<<<Npad / 32, 256, 0, stream>>>(X, Wihb, Whhb, bif, bhf, d_out, flag, N);
}